// Round 7
// baseline (404.471 us; speedup 1.0000x reference)
//
#include <hip/hip_runtime.h>
#include <cstdint>
#include <cstddef>

#define LN_EPS 1e-5f

typedef short bf16x8 __attribute__((ext_vector_type(8)));
typedef float f32x4 __attribute__((ext_vector_type(4)));

typedef const __attribute__((address_space(1))) void* gptr_t;
typedef __attribute__((address_space(3))) void* lptr_t;

__device__ __forceinline__ uint16_t f2bf(float f){
  uint32_t u = __float_as_uint(f);
  u += 0x7fffu + ((u >> 16) & 1u);
  return (uint16_t)(u >> 16);
}
__device__ __forceinline__ float bf2f(uint16_t h){
  return __uint_as_float(((uint32_t)h) << 16);
}
__device__ __forceinline__ float sigm(float x){
  return __builtin_amdgcn_rcpf(1.0f + __expf(-x));
}

// ---------------- K0: convert 6 weight matrices (128x128 fp32) to bf16 ----------------
// order: 0=left_proj_w 1=left_gate_w 2=right_proj_w 3=right_gate_w 4=gating_w 5=out_proj_w
__global__ __launch_bounds__(256) void wconv_k(
    const float* __restrict__ w0, const float* __restrict__ w1,
    const float* __restrict__ w2, const float* __restrict__ w3,
    const float* __restrict__ w4, const float* __restrict__ w5,
    uint16_t* __restrict__ dst)
{
  int i = blockIdx.x*256 + threadIdx.x;   // 6*16384 total
  int m = i >> 14, e = i & 16383;
  const float* s = (m==0)?w0:(m==1)?w1:(m==2)?w2:(m==3)?w3:(m==4)?w4:w5;
  dst[i] = f2bf(s[e]);
}

// ---------------- K1: LN + 5 projections, wave-specialized, W-in-registers ----------------
// 1024 blocks x 768 threads (12 waves); block owns 256 positions (= half a row i) as 4 tiles of 64.
// Waves 0-3: left proj+gate; 4-7: right; 8-11: gating + LN of next tile (x[32] held in regs, R4).
// NO transpose LDS: acc lanes hold 4 consecutive p for fixed c -> direct 8B c-major global stores.
// leftT/rightT written PRE-SWIZZLED (byte ^ (i&7)<<4 within each 128B k-block) so k2 can stage
// with linear global_load_lds. gbuf written plain c-major (k3 reads it contiguously).
// LDS: sA[2] 32KB + masks => ~33KB; VGPR target <=84 -> 2 blocks/CU (24 waves).
__global__ __launch_bounds__(768, 3) void k1_proj(
    const float* __restrict__ act, const float* __restrict__ mask,
    const float* __restrict__ lnw, const float* __restrict__ lnb,
    const float* __restrict__ lpb, const float* __restrict__ lgB,
    const float* __restrict__ rpb, const float* __restrict__ rgB,
    const float* __restrict__ gB,
    const uint16_t* __restrict__ wbf,
    uint16_t* __restrict__ leftT, uint16_t* __restrict__ rightT,
    uint16_t* __restrict__ gbuf)
{
  __shared__ uint16_t sA[2][64*128];      // 32KB, [row64][c128] bf16 swizzled
  __shared__ float sMask[2][64];
  const int t = threadIdx.x;
  const int lane = t & 63, wid = t >> 6;
  const int p0 = blockIdx.x * 256;
  const int i_row = blockIdx.x >> 1;          // global i of this block (uniform)
  const int kbase = (blockIdx.x & 1) * 256;   // k-offset of block within row i
  const int swz = (i_row & 7) << 4;           // pre-swizzle XOR (uniform per block)
  const int l15 = lane & 15, lh = lane >> 4;
  const bool isG = (wid >= 8);
  const int fam = wid >> 2;               // 0=L, 1=R, 2=G
  const int cbase = (wid & 3) * 32;
  const f32x4 z4 = {0.f,0.f,0.f,0.f};

  // ---- persistent W fragments (loaded once) ----
  bf16x8 Wp[2][4], Wg[2][4];
  {
    const int m0 = (fam==0)?0:(fam==1)?2:4;
#pragma unroll
    for(int tn=0;tn<2;tn++){
      const int o = cbase + tn*16 + l15;
#pragma unroll
      for(int ks=0;ks<4;ks++)
        Wp[tn][ks] = *(const bf16x8*)(wbf + m0*16384 + o*128 + ks*32 + lh*8);
    }
    if(!isG){
#pragma unroll
      for(int tn=0;tn<2;tn++){
        const int o = cbase + tn*16 + l15;
#pragma unroll
        for(int ks=0;ks<4;ks++)
          Wg[tn][ks] = *(const bf16x8*)(wbf + (m0+1)*16384 + o*128 + ks*32 + lh*8);
      }
    }
  }
  // ---- biases (persistent scalars) ----
  float pbv[2], gbv[2];
  {
    const float* pb  = (fam==0)? lpb : (fam==1)? rpb : gB;
    const float* gb2 = (fam==0)? lgB : rgB;
#pragma unroll
    for(int tn=0;tn<2;tn++){
      const int c = cbase + tn*16 + l15;
      pbv[tn] = pb[c];
      gbv[tn] = isG ? 0.f : gb2[c];
    }
  }

  float x[32];        // G-wave LN staging (held across gemm, R4-style)
  float mval = 0.f;

  auto ln_load = [&](int tile){
    const int g = t - 512, row = g >> 2, q = g & 3;
    const float* src = act + (size_t)(p0 + tile*64 + row)*128 + q*32;
#pragma unroll
    for(int u=0;u<8;u++){
      float4 v = *(const float4*)(src + u*4);
      x[u*4+0]=v.x; x[u*4+1]=v.y; x[u*4+2]=v.z; x[u*4+3]=v.w;
    }
    if(q==0) mval = mask[p0 + tile*64 + row];
  };
  auto ln_finish = [&](int nb){
    const int g = t - 512, row = g >> 2, q = g & 3;
    float s=0.f, s2=0.f;
#pragma unroll
    for(int u=0;u<32;u++){ s += x[u]; s2 += x[u]*x[u]; }
    s  += __shfl_xor(s,1);  s  += __shfl_xor(s,2);
    s2 += __shfl_xor(s2,1); s2 += __shfl_xor(s2,2);
    const float mu   = s * (1.f/128.f);
    const float var  = s2 * (1.f/128.f) - mu*mu;
    const float rstd = rsqrtf(var + LN_EPS);
    const int rs = (row&7)<<4;
#pragma unroll
    for(int u=0;u<4;u++){
      const int c0 = q*32 + u*8;
      float4 w0 = *(const float4*)(lnw + c0), w1 = *(const float4*)(lnw + c0 + 4);
      float4 b0 = *(const float4*)(lnb + c0), b1 = *(const float4*)(lnb + c0 + 4);
      uint16_t h[8];
      h[0]=f2bf((x[u*8+0]-mu)*rstd*w0.x+b0.x); h[1]=f2bf((x[u*8+1]-mu)*rstd*w0.y+b0.y);
      h[2]=f2bf((x[u*8+2]-mu)*rstd*w0.z+b0.z); h[3]=f2bf((x[u*8+3]-mu)*rstd*w0.w+b0.w);
      h[4]=f2bf((x[u*8+4]-mu)*rstd*w1.x+b1.x); h[5]=f2bf((x[u*8+5]-mu)*rstd*w1.y+b1.y);
      h[6]=f2bf((x[u*8+6]-mu)*rstd*w1.z+b1.z); h[7]=f2bf((x[u*8+7]-mu)*rstd*w1.w+b1.w);
      uint4 pk;
      pk.x = (uint32_t)h[0] | ((uint32_t)h[1]<<16);
      pk.y = (uint32_t)h[2] | ((uint32_t)h[3]<<16);
      pk.z = (uint32_t)h[4] | ((uint32_t)h[5]<<16);
      pk.w = (uint32_t)h[6] | ((uint32_t)h[7]<<16);
      *(uint4*)((char*)sA[nb] + row*256 + ((c0*2) ^ rs)) = pk;
    }
    if(q==0) sMask[nb][row] = mval;
  };

  // ---- gemm + fused epilogue + DIRECT c-major global stores for one 64-row tile ----
  uint16_t* dstT = (fam==0)? leftT : rightT;
  auto work = [&](int cb, int mt){
    const int ktile = kbase + mt*64;          // k-block start for L/R; p-offset for G
#pragma unroll
    for(int rt=0; rt<4; rt++){
      bf16x8 af[4];
      const int arow = rt*16 + l15;
      const int ars = (arow&7)<<4;
#pragma unroll
      for(int ks=0;ks<4;ks++)
        af[ks] = *(const bf16x8*)((const char*)sA[cb] + arow*256 + ((ks*64+lh*16) ^ ars));
      f32x4 aP[2] = {z4,z4}, aQ[2] = {z4,z4};
      if(isG){
#pragma unroll
        for(int ks=0;ks<4;ks++)
#pragma unroll
          for(int tn=0;tn<2;tn++)
            aP[tn] = __builtin_amdgcn_mfma_f32_16x16x32_bf16(af[ks], Wp[tn][ks], aP[tn], 0,0,0);
      } else {
#pragma unroll
        for(int ks=0;ks<4;ks++)
#pragma unroll
          for(int tn=0;tn<2;tn++){
            aP[tn] = __builtin_amdgcn_mfma_f32_16x16x32_bf16(af[ks], Wp[tn][ks], aP[tn], 0,0,0);
            aQ[tn] = __builtin_amdgcn_mfma_f32_16x16x32_bf16(af[ks], Wg[tn][ks], aQ[tn], 0,0,0);
          }
      }
      const int prow = rt*16 + lh*4;          // lane's 4 consecutive p (k-positions)
#pragma unroll
      for(int tn=0;tn<2;tn++){
        const int c = cbase + tn*16 + l15;
        uint16_t h[4];
        if(isG){
#pragma unroll
          for(int r=0;r<4;r++)
            h[r] = f2bf(sigm(aP[tn][r] + pbv[tn]));
        } else {
#pragma unroll
          for(int r=0;r<4;r++)
            h[r] = f2bf(sMask[cb][prow+r]*(aP[tn][r]+pbv[tn]) * sigm(aQ[tn][r]+gbv[tn]));
        }
        uint2 pk;
        pk.x = (uint32_t)h[0] | ((uint32_t)h[1]<<16);
        pk.y = (uint32_t)h[2] | ((uint32_t)h[3]<<16);
        if(isG){
          *(uint2*)(gbuf + (size_t)c*262144 + p0 + mt*64 + prow) = pk;
        } else {
          const int koff = ((prow*2) ^ swz) >> 1;     // pre-swizzled position in k-block
          *(uint2*)(dstT + (size_t)c*262144 + (size_t)i_row*512 + ktile + koff) = pk;
        }
      }
    }
  };

  // ---- prologue: G waves LN tile 0 into buffer 0 ----
  if(isG){
    ln_load(0);
    ln_finish(0);
  }
  __syncthreads();

  // ---- main loop: 4 tiles, 1 barrier per tile ----
  for(int mt=0; mt<4; mt++){
    const int cb = mt & 1;
    if(isG && mt < 3) ln_load(mt+1);          // global loads overlap work below
    work(cb, mt);                             // gemm + epi + direct stores
    if(isG && mt < 3) ln_finish(cb^1);        // sA for next tile
    __syncthreads();
  }
}

// ---------------- K2: triangle einsum, 128 c-batched 512x512x512 GEMMs ----------------
// 2048 blocks (XCD-chunk swizzled), tile 128x128, BK=64. Staging via async global_load_lds:
// leftT/rightT are PRE-SWIZZLED in global, so the linear wave copy lands the XOR-swizzled
// LDS layout the MFMA reads expect (no VGPR roundtrip, no ds_writes).
__global__ __launch_bounds__(256) void k2_tri(
    const uint16_t* __restrict__ leftT, const uint16_t* __restrict__ rightT,
    uint16_t* __restrict__ tbuf)
{
  __shared__ uint16_t sm[2*8192];   // 32KB: sL | sR; reused as [128][128] C-tile in epilogue
  uint16_t* sL = sm;
  uint16_t* sR = sm + 8192;
  // XCD-chunked bijective swizzle: 2048 = 8 * 256
  const int bx = (blockIdx.x & 7)*256 + (blockIdx.x >> 3);
  const int c = bx >> 4, it = (bx >> 2) & 3, jt = bx & 3;
  const char* Lb = (const char*)(leftT  + (size_t)c*262144) + (size_t)it*128*1024;
  const char* Rb = (const char*)(rightT + (size_t)c*262144) + (size_t)jt*128*1024;
  const int t = threadIdx.x, lane = t & 63, wid = t >> 6;
  const int wm = wid >> 1, wn = wid & 1;   // wave: 64x64 of the 128x128 tile
  const int l15 = lane & 15, lh = lane >> 4;
  const f32x4 z4 = {0.f,0.f,0.f,0.f};
  f32x4 acc[4][4];
#pragma unroll
  for(int a=0;a<4;a++) for(int b=0;b<4;b++) acc[a][b]=z4;

  const int qbase = wid*4;                 // wave's 4 chunks (1KB each) per matrix
  const int lrow = lane >> 3;              // lane's row within 8-row chunk
  const int lkb  = (lane & 7) * 16;        // lane's 16B within 128B row

  for(int kt=0; kt<8; kt++){
    __syncthreads();                       // previous compute done before overwrite
#pragma unroll
    for(int u=0;u<4;u++){
      const int qq = qbase + u;
      const size_t roff = (size_t)(qq*8 + lrow)*1024 + (size_t)kt*128 + lkb;
      __builtin_amdgcn_global_load_lds((gptr_t)(Lb + roff),
                                       (lptr_t)(void*)((char*)sL + qq*1024), 16, 0, 0);
      __builtin_amdgcn_global_load_lds((gptr_t)(Rb + roff),
                                       (lptr_t)(void*)((char*)sR + qq*1024), 16, 0, 0);
    }
    __syncthreads();                       // vmcnt drained by barrier -> LDS ready
#pragma unroll
    for(int ks=0;ks<2;ks++){
      bf16x8 af[4], bv[4];
#pragma unroll
      for(int tm=0;tm<4;tm++){
        const int row = wm*64 + tm*16 + l15;
        const int byte = row*128 + ((ks*64 + lh*16) ^ ((row&7)<<4));
        af[tm] = *(const bf16x8*)((const char*)sL + byte);
      }
#pragma unroll
      for(int tn=0;tn<4;tn++){
        const int row = wn*64 + tn*16 + l15;
        const int byte = row*128 + ((ks*64 + lh*16) ^ ((row&7)<<4));
        bv[tn] = *(const bf16x8*)((const char*)sR + byte);
      }
#pragma unroll
      for(int tm=0;tm<4;tm++)
#pragma unroll
        for(int tn=0;tn<4;tn++)
          acc[tm][tn] = __builtin_amdgcn_mfma_f32_16x16x32_bf16(af[tm], bv[tn], acc[tm][tn], 0,0,0);
    }
  }
  // epilogue: scatter into LDS [i][j] tile, then coalesced 128B-contiguous stores
  __syncthreads();
#pragma unroll
  for(int tm=0;tm<4;tm++){
#pragma unroll
    for(int tn=0;tn<4;tn++){
      const int j = wn*64 + tn*16 + l15;
#pragma unroll
      for(int r=0;r<4;r++){
        const int i = wm*64 + tm*16 + lh*4 + r;
        const int byte = i*256 + ((j*2) ^ ((i&7)<<4));
        *(uint16_t*)((char*)sm + byte) = f2bf(acc[tm][tn][r]);
      }
    }
  }
  __syncthreads();
  {
    const int i = t >> 1, half = (t & 1)*64;
    uint16_t* dst = tbuf + (size_t)c*262144 + (size_t)(it*128+i)*512 + jt*128 + half;
#pragma unroll
    for(int u=0;u<8;u++){
      const int byte = i*256 + ((half*2 + u*16) ^ ((i&7)<<4));
      *(uint4*)(dst + u*8) = *(const uint4*)((const char*)sm + byte);
    }
  }
}

// ---------------- K3: LN_c + out_proj + gating multiply (BW-bound, at roofline) ----------------
__global__ __launch_bounds__(256) void k3_out(
    const uint16_t* __restrict__ tbuf, const uint16_t* __restrict__ gbuf,
    const float* __restrict__ lncw, const float* __restrict__ lncb,
    const uint16_t* __restrict__ wbf, const float* __restrict__ opb,
    float* __restrict__ out)
{
  __shared__ uint16_t sT2[64*128];  // 16KB [p 64][c 128] bf16, swizzled
  __shared__ uint16_t sG[64*128];   // 16KB [p 64][c 128] bf16, swizzled
  const int bx = blockIdx.x;
  const int i = bx >> 3, j0 = (bx & 7)*64;
  const int t = threadIdx.x;
  const int pbase = i*512 + j0;

  { // transpose-load t and g: thread -> (c = t>>1, 32 consecutive j), 64B coalesced reads
    const int c = t >> 1, ph = (t & 1)*32;
    const uint16_t* srcT = tbuf + (size_t)c*262144 + pbase + ph;
    const uint16_t* srcG = gbuf + (size_t)c*262144 + pbase + ph;
#pragma unroll
    for(int u=0;u<4;u++){
      uint4 v = *(const uint4*)(srcT + u*8);
      uint4 g = *(const uint4*)(srcG + u*8);
      uint16_t et[8], eg[8];
      et[0]=(uint16_t)(v.x&0xffff); et[1]=(uint16_t)(v.x>>16);
      et[2]=(uint16_t)(v.y&0xffff); et[3]=(uint16_t)(v.y>>16);
      et[4]=(uint16_t)(v.z&0xffff); et[5]=(uint16_t)(v.z>>16);
      et[6]=(uint16_t)(v.w&0xffff); et[7]=(uint16_t)(v.w>>16);
      eg[0]=(uint16_t)(g.x&0xffff); eg[1]=(uint16_t)(g.x>>16);
      eg[2]=(uint16_t)(g.y&0xffff); eg[3]=(uint16_t)(g.y>>16);
      eg[4]=(uint16_t)(g.z&0xffff); eg[5]=(uint16_t)(g.z>>16);
      eg[6]=(uint16_t)(g.w&0xffff); eg[7]=(uint16_t)(g.w>>16);
#pragma unroll
      for(int k2=0;k2<8;k2++){
        const int p = ph + u*8 + k2;
        const int byte = p*256 + ((c*2) ^ ((p&7)<<4));
        *(uint16_t*)((char*)sT2 + byte) = et[k2];
        *(uint16_t*)((char*)sG + byte) = eg[k2];
      }
    }
  }
  __syncthreads();

  const int lane = t & 63, wid = t >> 6;
  { // LayerNorm over c per position row (fp32), 4 lanes per row
    const int row = wid*16 + (lane & 15);
    const int q = lane >> 4;
    float xs[32];
#pragma unroll
    for(int u=0;u<4;u++){
      const int kb = q*64 + u*16;
      const int byte = row*256 + (kb ^ ((row&7)<<4));
      uint4 v = *(const uint4*)((const char*)sT2 + byte);
      xs[u*8+0]=bf2f((uint16_t)(v.x&0xffff)); xs[u*8+1]=bf2f((uint16_t)(v.x>>16));
      xs[u*8+2]=bf2f((uint16_t)(v.y&0xffff)); xs[u*8+3]=bf2f((uint16_t)(v.y>>16));
      xs[u*8+4]=bf2f((uint16_t)(v.z&0xffff)); xs[u*8+5]=bf2f((uint16_t)(v.z>>16));
      xs[u*8+6]=bf2f((uint16_t)(v.w&0xffff)); xs[u*8+7]=bf2f((uint16_t)(v.w>>16));
    }
    float s=0.f, s2=0.f;
#pragma unroll
    for(int u=0;u<32;u++){ s += xs[u]; s2 += xs[u]*xs[u]; }
    s  += __shfl_xor(s,16);  s  += __shfl_xor(s,32);
    s2 += __shfl_xor(s2,16); s2 += __shfl_xor(s2,32);
    const float mu   = s * (1.f/128.f);
    const float var  = s2 * (1.f/128.f) - mu*mu;
    const float rstd = rsqrtf(var + LN_EPS);
#pragma unroll
    for(int u=0;u<4;u++){
      const int kb = q*64 + u*16;
      const int c0 = (kb ^ ((row&7)<<4)) >> 1;    // de-swizzled channel of this 16B block
      uint16_t h[8];
#pragma unroll
      for(int j=0;j<8;j++)
        h[j] = f2bf((xs[u*8+j]-mu)*rstd*lncw[c0+j] + lncb[c0+j]);
      uint4 pk;
      pk.x = (uint32_t)h[0] | ((uint32_t)h[1]<<16);
      pk.y = (uint32_t)h[2] | ((uint32_t)h[3]<<16);
      pk.z = (uint32_t)h[4] | ((uint32_t)h[5]<<16);
      pk.w = (uint32_t)h[6] | ((uint32_t)h[7]<<16);
      const int byte = row*256 + (kb ^ ((row&7)<<4));
      *(uint4*)((char*)sT2 + byte) = pk;
    }
  }
  __syncthreads();

  const int wm = wid >> 1, wn = wid & 1;
  const int l15 = lane & 15, lh = lane >> 4;
  const f32x4 z4 = {0.f,0.f,0.f,0.f};
  const uint16_t* W = wbf + 5*16384;   // out_proj_w bf16
  f32x4 acc[2][4];
#pragma unroll
  for(int a=0;a<2;a++) for(int b=0;b<4;b++) acc[a][b]=z4;
#pragma unroll
  for(int ks=0;ks<4;ks++){
    bf16x8 af[2];
#pragma unroll
    for(int tm=0;tm<2;tm++){
      const int row = wm*32 + tm*16 + l15;
      const int byte = row*256 + ((ks*64 + lh*16) ^ ((row&7)<<4));
      af[tm] = *(const bf16x8*)((const char*)sT2 + byte);
    }
#pragma unroll
    for(int tn=0;tn<4;tn++){
      const int o = wn*64 + tn*16 + l15;
      const bf16x8 bv = *(const bf16x8*)(W + o*128 + ks*32 + lh*8);
#pragma unroll
      for(int tm=0;tm<2;tm++)
        acc[tm][tn] = __builtin_amdgcn_mfma_f32_16x16x32_bf16(af[tm], bv, acc[tm][tn], 0,0,0);
    }
  }
#pragma unroll
  for(int tm=0;tm<2;tm++){
#pragma unroll
    for(int tn=0;tn<4;tn++){
      const int col = wn*64 + tn*16 + l15;
      const float obv = opb[col];
#pragma unroll
      for(int r=0;r<4;r++){
        const int row = wm*32 + tm*16 + lh*4 + r;
        const size_t p = (size_t)(pbase + row);
        const int gbyte = row*256 + ((col*2) ^ ((row&7)<<4));
        const float gv = bf2f(*(const uint16_t*)((const char*)sG + gbyte));
        out[p*128 + col] = (acc[tm][tn][r] + obv) * gv;
      }
    }
  }
}

// ---------------- launch ----------------
extern "C" void kernel_launch(void* const* d_in, const int* in_sizes, int n_in,
                              void* d_out, int out_size, void* d_ws, size_t ws_size,
                              hipStream_t stream)
{
  (void)in_sizes; (void)n_in; (void)out_size; (void)ws_size;
  const float* act   = (const float*)d_in[0];
  const float* mask  = (const float*)d_in[1];
  const float* lnw   = (const float*)d_in[2];
  const float* lnb   = (const float*)d_in[3];
  const float* lpw   = (const float*)d_in[4];
  const float* lpb   = (const float*)d_in[5];
  const float* rpw   = (const float*)d_in[6];
  const float* rpb   = (const float*)d_in[7];
  const float* lgw   = (const float*)d_in[8];
  const float* lgb   = (const float*)d_in[9];
  const float* rgw   = (const float*)d_in[10];
  const float* rgb   = (const float*)d_in[11];
  const float* lncw  = (const float*)d_in[12];
  const float* lncb  = (const float*)d_in[13];
  const float* opw   = (const float*)d_in[14];
  const float* opb   = (const float*)d_in[15];
  const float* gw    = (const float*)d_in[16];
  const float* gb    = (const float*)d_in[17];

  char* ws = (char*)d_ws;
  uint16_t* leftT  = (uint16_t*)(ws);                      // 64MB [C][N*N] bf16, PRE-SWIZZLED
  uint16_t* rightT = (uint16_t*)(ws + ((size_t)64<<20));   // 64MB, PRE-SWIZZLED
  uint16_t* gbuf   = (uint16_t*)(ws + ((size_t)128<<20));  // 64MB [C][N*N] bf16 plain c-major
  uint16_t* tbuf   = (uint16_t*)(ws + ((size_t)192<<20));  // 64MB [C][N*N] bf16 plain
  uint16_t* wbf    = (uint16_t*)(ws + ((size_t)256<<20));  // 192KB: 6 bf16 weight mats

  wconv_k<<<384, 256, 0, stream>>>(lpw, lgw, rpw, rgw, gw, opw, wbf);
  k1_proj<<<1024, 768, 0, stream>>>(act, mask, lnw, lnb, lpb, lgb, rpb, rgb, gb,
                                    wbf, leftT, rightT, gbuf);
  k2_tri<<<2048, 256, 0, stream>>>(leftT, rightT, tbuf);
  k3_out<<<4096, 256, 0, stream>>>(tbuf, gbuf, lncw, lncb, wbf, opb, (float*)d_out);
}

// Round 9
// 348.308 us; speedup vs baseline: 1.1612x; 1.1612x over previous
//
#include <hip/hip_runtime.h>
#include <hip/hip_fp16.h>
#include <cstdint>
#include <cstddef>

#define LN_EPS 1e-5f

typedef short bf16x8 __attribute__((ext_vector_type(8)));
typedef float f32x4 __attribute__((ext_vector_type(4)));

typedef const __attribute__((address_space(1))) void* gptr_t;
typedef __attribute__((address_space(3))) void* lptr_t;

__device__ __forceinline__ uint16_t f2bf(float f){
  uint32_t u = __float_as_uint(f);
  u += 0x7fffu + ((u >> 16) & 1u);
  return (uint16_t)(u >> 16);
}
__device__ __forceinline__ float bf2f(uint16_t h){
  return __uint_as_float(((uint32_t)h) << 16);
}
// fp16 carriers for the inter-wave sigmoid hand-off (10 mantissa bits vs bf16's 7;
// sigmoid in (0,1) is perfectly ranged for fp16 -> quantization error negligible)
__device__ __forceinline__ uint16_t f2h(float f){
  __half h = __float2half(f);
  return *reinterpret_cast<uint16_t*>(&h);
}
__device__ __forceinline__ float h2f(uint16_t u){
  __half h = *reinterpret_cast<__half*>(&u);
  return __half2float(h);
}
__device__ __forceinline__ float sigm(float x){
  return __builtin_amdgcn_rcpf(1.0f + __expf(-x));
}

// ---------------- K0: convert 6 weight matrices (128x128 fp32) to bf16 ----------------
// order: 0=left_proj_w 1=left_gate_w 2=right_proj_w 3=right_gate_w 4=gating_w 5=out_proj_w
__global__ __launch_bounds__(256) void wconv_k(
    const float* __restrict__ w0, const float* __restrict__ w1,
    const float* __restrict__ w2, const float* __restrict__ w3,
    const float* __restrict__ w4, const float* __restrict__ w5,
    uint16_t* __restrict__ dst)
{
  int i = blockIdx.x*256 + threadIdx.x;   // 6*16384 total
  int m = i >> 14, e = i & 16383;
  const float* s = (m==0)?w0:(m==1)?w1:(m==2)?w2:(m==3)?w3:(m==4)?w4:w5;
  dst[i] = f2bf(s[e]);
}

// ---------------- K1: LN + left/right proj*sigmoid(gate), 16-wave blocks ----------------
// 1024 blocks x 1024 threads (16 waves); block owns 256 p (= half row i) as 4 tiles of 64.
// Wave job = (matrix, 32-col slice): fam = wid>>2 in {Lp,Lg,Rp,Rg}, slice = wid&3.
// W = 32 VGPR/wave. Gate waves: MFMA -> sigmoid -> **fp16** into sTS; B1; proj waves
// combine IN-PLACE (fp32 math, single bf16 round); B2; all waves readout
// (full-128B-line pre-swizzled stores); gate waves LN next tile; B3.
// Gating matrix lives in K3. Outputs leftT/rightT c-major [C][N*N], PRE-SWIZZLED per
// 128B k-block (byte ^ (i&7)<<4) for k2's linear global_load_lds.
__global__ __launch_bounds__(1024) void k1_proj(
    const float* __restrict__ act, const float* __restrict__ mask,
    const float* __restrict__ lnw, const float* __restrict__ lnb,
    const float* __restrict__ lpb, const float* __restrict__ lgB,
    const float* __restrict__ rpb, const float* __restrict__ rgB,
    const uint16_t* __restrict__ wbf,
    uint16_t* __restrict__ leftT, uint16_t* __restrict__ rightT)
{
  __shared__ uint16_t sA[2][64*128];     // 32KB [row64][c128] bf16 swizzled, dbuf
  __shared__ uint16_t sTS[2][128*64];    // 32KB [famLR][c128][p64] swizzled (fp16 sig -> bf16 final)
  __shared__ float sMask[2][64];
  const int t = threadIdx.x;
  const int lane = t & 63, wid = t >> 6;
  const int p0 = blockIdx.x * 256;
  const int i_row = blockIdx.x >> 1;
  const int kbase = (blockIdx.x & 1) * 256;
  const int swz = (i_row & 7) << 4;
  const int l15 = lane & 15, lh = lane >> 4;
  const int fam = wid >> 2;              // 0=Lp 1=Lg 2=Rp 3=Rg
  const bool isGate = fam & 1;
  const int famLR = fam >> 1;
  const int cbase = (wid & 3) * 32;
  const f32x4 z4 = {0.f,0.f,0.f,0.f};

  // ---- persistent W fragments: ONE matrix, 32 cols -> 32 VGPRs ----
  bf16x8 Wm[2][4];
#pragma unroll
  for(int tn=0;tn<2;tn++){
    const int o = cbase + tn*16 + l15;
#pragma unroll
    for(int ks=0;ks<4;ks++)
      Wm[tn][ks] = *(const bf16x8*)(wbf + fam*16384 + o*128 + ks*32 + lh*8);
  }
  // ---- bias ----
  float bv[2];
  {
    const float* bp = (fam==0)? lpb : (fam==1)? lgB : (fam==2)? rpb : rgB;
#pragma unroll
    for(int tn=0;tn<2;tn++) bv[tn] = bp[cbase + tn*16 + l15];
  }

  // ---- gate-wave LN (8 waves, 8 thr/row, x[16] held) ----
  const int gwid = (wid < 8)? (wid - 4) : (wid - 8);   // 0..7 for gate waves
  const int gt = gwid*64 + lane;
  const int lrow = gt >> 3, lq = gt & 7;
  float x[16]; float mv = 0.f;

  auto ln_load = [&](int tile){
    const float* src = act + (size_t)(p0 + tile*64 + lrow)*128 + lq*16;
#pragma unroll
    for(int u=0;u<4;u++){
      float4 v = *(const float4*)(src + u*4);
      x[u*4+0]=v.x; x[u*4+1]=v.y; x[u*4+2]=v.z; x[u*4+3]=v.w;
    }
    if(lq==0) mv = mask[p0 + tile*64 + lrow];
  };
  auto ln_finish = [&](int nb){
    float s=0.f, s2=0.f;
#pragma unroll
    for(int u=0;u<16;u++){ s += x[u]; s2 += x[u]*x[u]; }
    s  += __shfl_xor(s,1);  s  += __shfl_xor(s,2);  s  += __shfl_xor(s,4);
    s2 += __shfl_xor(s2,1); s2 += __shfl_xor(s2,2); s2 += __shfl_xor(s2,4);
    const float mu   = s * (1.f/128.f);
    const float var  = s2 * (1.f/128.f) - mu*mu;
    const float rstd = rsqrtf(var + LN_EPS);
    const int rs = (lrow&7)<<4;
#pragma unroll
    for(int u=0;u<2;u++){
      const int c0 = lq*16 + u*8;
      float4 w0 = *(const float4*)(lnw + c0), w1 = *(const float4*)(lnw + c0 + 4);
      float4 b0 = *(const float4*)(lnb + c0), b1 = *(const float4*)(lnb + c0 + 4);
      uint16_t h[8];
      h[0]=f2bf((x[u*8+0]-mu)*rstd*w0.x+b0.x); h[1]=f2bf((x[u*8+1]-mu)*rstd*w0.y+b0.y);
      h[2]=f2bf((x[u*8+2]-mu)*rstd*w0.z+b0.z); h[3]=f2bf((x[u*8+3]-mu)*rstd*w0.w+b0.w);
      h[4]=f2bf((x[u*8+4]-mu)*rstd*w1.x+b1.x); h[5]=f2bf((x[u*8+5]-mu)*rstd*w1.y+b1.y);
      h[6]=f2bf((x[u*8+6]-mu)*rstd*w1.z+b1.z); h[7]=f2bf((x[u*8+7]-mu)*rstd*w1.w+b1.w);
      uint4 pk;
      pk.x = (uint32_t)h[0] | ((uint32_t)h[1]<<16);
      pk.y = (uint32_t)h[2] | ((uint32_t)h[3]<<16);
      pk.z = (uint32_t)h[4] | ((uint32_t)h[5]<<16);
      pk.w = (uint32_t)h[6] | ((uint32_t)h[7]<<16);
      *(uint4*)((char*)sA[nb] + lrow*256 + ((c0*2) ^ rs)) = pk;
    }
    if(lq==0) sMask[nb][lrow] = mv;
  };

  // ---- prologue ----
  if(isGate){
    ln_load(0);
    ln_finish(0);
  }
  __syncthreads();

  uint16_t* sTSf = sTS[famLR];

  for(int mt=0; mt<4; mt++){
    const int cur = mt & 1;
    // ---- MFMA phase; gate waves drop fp16 sigmoid into sTS per rt ----
    f32x4 accP[4][2];
#pragma unroll
    for(int rt=0; rt<4; rt++){
      bf16x8 af[4];
      const int arow = rt*16 + l15;
      const int ars = (arow&7)<<4;
#pragma unroll
      for(int ks=0;ks<4;ks++)
        af[ks] = *(const bf16x8*)((const char*)sA[cur] + arow*256 + ((ks*64+lh*16) ^ ars));
      f32x4 a0 = z4, a1 = z4;
#pragma unroll
      for(int ks=0;ks<4;ks++){
        a0 = __builtin_amdgcn_mfma_f32_16x16x32_bf16(af[ks], Wm[0][ks], a0, 0,0,0);
        a1 = __builtin_amdgcn_mfma_f32_16x16x32_bf16(af[ks], Wm[1][ks], a1, 0,0,0);
      }
      const int prow = rt*16 + lh*4;
      if(isGate){
#pragma unroll
        for(int tn=0;tn<2;tn++){
          const f32x4 av = tn ? a1 : a0;
          const int c = cbase + tn*16 + l15;
          uint16_t h[4];
#pragma unroll
          for(int r=0;r<4;r++) h[r] = f2h(sigm(av[r] + bv[tn]));   // fp16 carrier
          uint2 pk;
          pk.x = (uint32_t)h[0] | ((uint32_t)h[1]<<16);
          pk.y = (uint32_t)h[2] | ((uint32_t)h[3]<<16);
          *(uint2*)((char*)sTSf + c*128 + ((prow*2) ^ ((c&7)<<4))) = pk;
        }
      } else {
        accP[rt][0] = a0; accP[rt][1] = a1;
      }
    }
    __syncthreads();                                   // B1: sig ready
    if(!isGate){
      // ---- combine in-place: mask*(proj+b)*sig, fp32 math, single bf16 round ----
#pragma unroll
      for(int rt=0; rt<4; rt++){
        const int prow = rt*16 + lh*4;
#pragma unroll
        for(int tn=0;tn<2;tn++){
          const int c = cbase + tn*16 + l15;
          char* addr = (char*)sTSf + c*128 + ((prow*2) ^ ((c&7)<<4));
          const uint2 sg = *(const uint2*)addr;
          float sf[4];
          sf[0]=h2f((uint16_t)(sg.x&0xffff)); sf[1]=h2f((uint16_t)(sg.x>>16));
          sf[2]=h2f((uint16_t)(sg.y&0xffff)); sf[3]=h2f((uint16_t)(sg.y>>16));
          uint16_t h[4];
#pragma unroll
          for(int r=0;r<4;r++)
            h[r] = f2bf(sMask[cur][prow+r]*(accP[rt][tn][r] + bv[tn]) * sf[r]);
          uint2 pk;
          pk.x = (uint32_t)h[0] | ((uint32_t)h[1]<<16);
          pk.y = (uint32_t)h[2] | ((uint32_t)h[3]<<16);
          *(uint2*)addr = pk;
        }
      }
    } else if(mt < 3){
      ln_load(mt+1);                                   // VMEM issue overlaps combine
    }
    __syncthreads();                                   // B2: sTS final
    { // ---- readout: 1024 threads over 2 fams x 128 c x 64 p, pre-swizzled stores ----
      const int fam2 = t >> 9;
      const int r9 = t & 511;
      const int c = r9 >> 2;
      const int g0 = (r9 & 3) * 32;                    // byte base of this thread's 32B
      const int cs = (c&7) << 4;
      const char* srcL = (const char*)sTS[fam2] + c*128;
      uint16_t* base = fam2 ? rightT : leftT;
      char* dst = (char*)(base + (size_t)c*262144 + (size_t)i_row*512 + kbase + mt*64);
#pragma unroll
      for(int u=0;u<2;u++){
        const int g = g0 + u*16;                       // global byte within 128B k-block
        uint4 q = *(const uint4*)(srcL + (g ^ swz ^ cs));
        *(uint4*)(dst + g) = q;
      }
    }
    if(isGate && mt < 3) ln_finish(cur^1);
    __syncthreads();                                   // B3: sA[next] ready, sTS free
  }
}

// ---------------- K2: triangle einsum, 128 c-batched 512x512x512 GEMMs ----------------
// 2048 blocks (XCD-chunk swizzled), tile 128x128, BK=64. Staging via async global_load_lds:
// leftT/rightT are PRE-SWIZZLED in global, so the linear wave copy lands the XOR-swizzled
// LDS layout the MFMA reads expect (no VGPR roundtrip, no ds_writes).
__global__ __launch_bounds__(256) void k2_tri(
    const uint16_t* __restrict__ leftT, const uint16_t* __restrict__ rightT,
    uint16_t* __restrict__ tbuf)
{
  __shared__ uint16_t sm[2*8192];   // 32KB: sL | sR; reused as [128][128] C-tile in epilogue
  uint16_t* sL = sm;
  uint16_t* sR = sm + 8192;
  // XCD-chunked bijective swizzle: 2048 = 8 * 256
  const int bx = (blockIdx.x & 7)*256 + (blockIdx.x >> 3);
  const int c = bx >> 4, it = (bx >> 2) & 3, jt = bx & 3;
  const char* Lb = (const char*)(leftT  + (size_t)c*262144) + (size_t)it*128*1024;
  const char* Rb = (const char*)(rightT + (size_t)c*262144) + (size_t)jt*128*1024;
  const int t = threadIdx.x, lane = t & 63, wid = t >> 6;
  const int wm = wid >> 1, wn = wid & 1;   // wave: 64x64 of the 128x128 tile
  const int l15 = lane & 15, lh = lane >> 4;
  const f32x4 z4 = {0.f,0.f,0.f,0.f};
  f32x4 acc[4][4];
#pragma unroll
  for(int a=0;a<4;a++) for(int b=0;b<4;b++) acc[a][b]=z4;

  const int qbase = wid*4;                 // wave's 4 chunks (1KB each) per matrix
  const int lrow = lane >> 3;              // lane's row within 8-row chunk
  const int lkb  = (lane & 7) * 16;        // lane's 16B within 128B row

  for(int kt=0; kt<8; kt++){
    __syncthreads();                       // previous compute done before overwrite
#pragma unroll
    for(int u=0;u<4;u++){
      const int qq = qbase + u;
      const size_t roff = (size_t)(qq*8 + lrow)*1024 + (size_t)kt*128 + lkb;
      __builtin_amdgcn_global_load_lds((gptr_t)(Lb + roff),
                                       (lptr_t)(void*)((char*)sL + qq*1024), 16, 0, 0);
      __builtin_amdgcn_global_load_lds((gptr_t)(Rb + roff),
                                       (lptr_t)(void*)((char*)sR + qq*1024), 16, 0, 0);
    }
    __syncthreads();                       // vmcnt drained by barrier -> LDS ready
#pragma unroll
    for(int ks=0;ks<2;ks++){
      bf16x8 af[4], bvv[4];
#pragma unroll
      for(int tm=0;tm<4;tm++){
        const int row = wm*64 + tm*16 + l15;
        const int byte = row*128 + ((ks*64 + lh*16) ^ ((row&7)<<4));
        af[tm] = *(const bf16x8*)((const char*)sL + byte);
      }
#pragma unroll
      for(int tn=0;tn<4;tn++){
        const int row = wn*64 + tn*16 + l15;
        const int byte = row*128 + ((ks*64 + lh*16) ^ ((row&7)<<4));
        bvv[tn] = *(const bf16x8*)((const char*)sR + byte);
      }
#pragma unroll
      for(int tm=0;tm<4;tm++)
#pragma unroll
        for(int tn=0;tn<4;tn++)
          acc[tm][tn] = __builtin_amdgcn_mfma_f32_16x16x32_bf16(af[tm], bvv[tn], acc[tm][tn], 0,0,0);
    }
  }
  // epilogue: scatter into LDS [i][j] tile, then coalesced 128B-contiguous stores
  __syncthreads();
#pragma unroll
  for(int tm=0;tm<4;tm++){
#pragma unroll
    for(int tn=0;tn<4;tn++){
      const int j = wn*64 + tn*16 + l15;
#pragma unroll
      for(int r=0;r<4;r++){
        const int i = wm*64 + tm*16 + lh*4 + r;
        const int byte = i*256 + ((j*2) ^ ((i&7)<<4));
        *(uint16_t*)((char*)sm + byte) = f2bf(acc[tm][tn][r]);
      }
    }
  }
  __syncthreads();
  {
    const int i = t >> 1, half = (t & 1)*64;
    uint16_t* dst = tbuf + (size_t)c*262144 + (size_t)(it*128+i)*512 + jt*128 + half;
#pragma unroll
    for(int u=0;u<8;u++){
      const int byte = i*256 + ((half*2 + u*16) ^ ((i&7)<<4));
      *(uint4*)(dst + u*8) = *(const uint4*)((const char*)sm + byte);
    }
  }
}

// ---------------- K3: LN_c + out_proj + fused gating (sigmoid(LN_in(act)@gw^T+gb)) ----------------
// grid 4096: block owns (i, j0..j0+63). Reads t (c-major) + act (p-major); writes fp32 out.
__global__ __launch_bounds__(256) void k3_out(
    const uint16_t* __restrict__ tbuf, const float* __restrict__ act,
    const float* __restrict__ lnw, const float* __restrict__ lnb,
    const float* __restrict__ lncw, const float* __restrict__ lncb,
    const uint16_t* __restrict__ wbf, const float* __restrict__ opb,
    const float* __restrict__ gB,
    float* __restrict__ out)
{
  __shared__ uint16_t sT2[64*128];  // 16KB [p 64][c 128] bf16, swizzled (t, then LN_c(t))
  __shared__ uint16_t sGA[64*128];  // 16KB [p 64][c 128] bf16, swizzled (LN_in(act))
  const int bx = blockIdx.x;
  const int i = bx >> 3, j0 = (bx & 7)*64;
  const int t = threadIdx.x;
  const int pbase = i*512 + j0;

  { // stage act + LN_in -> sGA: 4 thr/row, 32 c each (coalesced 128B row segments)
    const int row = t >> 2, q = t & 3;
    const float* src = act + (size_t)(pbase + row)*128 + q*32;
    float x[32];
#pragma unroll
    for(int u=0;u<8;u++){
      float4 v = *(const float4*)(src + u*4);
      x[u*4+0]=v.x; x[u*4+1]=v.y; x[u*4+2]=v.z; x[u*4+3]=v.w;
    }
    float s=0.f, s2=0.f;
#pragma unroll
    for(int u=0;u<32;u++){ s += x[u]; s2 += x[u]*x[u]; }
    s  += __shfl_xor(s,1);  s  += __shfl_xor(s,2);
    s2 += __shfl_xor(s2,1); s2 += __shfl_xor(s2,2);
    const float mu   = s * (1.f/128.f);
    const float var  = s2 * (1.f/128.f) - mu*mu;
    const float rstd = rsqrtf(var + LN_EPS);
    const int rs = (row&7)<<4;
#pragma unroll
    for(int u=0;u<4;u++){
      const int c0 = q*32 + u*8;
      float4 w0 = *(const float4*)(lnw + c0), w1 = *(const float4*)(lnw + c0 + 4);
      float4 b0 = *(const float4*)(lnb + c0), b1 = *(const float4*)(lnb + c0 + 4);
      uint16_t h[8];
      h[0]=f2bf((x[u*8+0]-mu)*rstd*w0.x+b0.x); h[1]=f2bf((x[u*8+1]-mu)*rstd*w0.y+b0.y);
      h[2]=f2bf((x[u*8+2]-mu)*rstd*w0.z+b0.z); h[3]=f2bf((x[u*8+3]-mu)*rstd*w0.w+b0.w);
      h[4]=f2bf((x[u*8+4]-mu)*rstd*w1.x+b1.x); h[5]=f2bf((x[u*8+5]-mu)*rstd*w1.y+b1.y);
      h[6]=f2bf((x[u*8+6]-mu)*rstd*w1.z+b1.z); h[7]=f2bf((x[u*8+7]-mu)*rstd*w1.w+b1.w);
      uint4 pk;
      pk.x = (uint32_t)h[0] | ((uint32_t)h[1]<<16);
      pk.y = (uint32_t)h[2] | ((uint32_t)h[3]<<16);
      pk.z = (uint32_t)h[4] | ((uint32_t)h[5]<<16);
      pk.w = (uint32_t)h[6] | ((uint32_t)h[7]<<16);
      *(uint4*)((char*)sGA + row*256 + ((c0*2) ^ rs)) = pk;
    }
  }
  { // transpose-load t: thread -> (c = t>>1, 32 consecutive j), 64B coalesced reads
    const int c = t >> 1, ph = (t & 1)*32;
    const uint16_t* srcT = tbuf + (size_t)c*262144 + pbase + ph;
#pragma unroll
    for(int u=0;u<4;u++){
      uint4 v = *(const uint4*)(srcT + u*8);
      uint16_t et[8];
      et[0]=(uint16_t)(v.x&0xffff); et[1]=(uint16_t)(v.x>>16);
      et[2]=(uint16_t)(v.y&0xffff); et[3]=(uint16_t)(v.y>>16);
      et[4]=(uint16_t)(v.z&0xffff); et[5]=(uint16_t)(v.z>>16);
      et[6]=(uint16_t)(v.w&0xffff); et[7]=(uint16_t)(v.w>>16);
#pragma unroll
      for(int k2=0;k2<8;k2++){
        const int p = ph + u*8 + k2;
        const int byte = p*256 + ((c*2) ^ ((p&7)<<4));
        *(uint16_t*)((char*)sT2 + byte) = et[k2];
      }
    }
  }
  __syncthreads();

  const int lane = t & 63, wid = t >> 6;
  { // LayerNorm_c over c per position row (fp32), in-place on sT2
    const int row = wid*16 + (lane & 15);
    const int q = lane >> 4;
    float xs[32];
#pragma unroll
    for(int u=0;u<4;u++){
      const int kb = q*64 + u*16;
      const int byte = row*256 + (kb ^ ((row&7)<<4));
      uint4 v = *(const uint4*)((const char*)sT2 + byte);
      xs[u*8+0]=bf2f((uint16_t)(v.x&0xffff)); xs[u*8+1]=bf2f((uint16_t)(v.x>>16));
      xs[u*8+2]=bf2f((uint16_t)(v.y&0xffff)); xs[u*8+3]=bf2f((uint16_t)(v.y>>16));
      xs[u*8+4]=bf2f((uint16_t)(v.z&0xffff)); xs[u*8+5]=bf2f((uint16_t)(v.z>>16));
      xs[u*8+6]=bf2f((uint16_t)(v.w&0xffff)); xs[u*8+7]=bf2f((uint16_t)(v.w>>16));
    }
    float s=0.f, s2=0.f;
#pragma unroll
    for(int u=0;u<32;u++){ s += xs[u]; s2 += xs[u]*xs[u]; }
    s  += __shfl_xor(s,16);  s  += __shfl_xor(s,32);
    s2 += __shfl_xor(s2,16); s2 += __shfl_xor(s2,32);
    const float mu   = s * (1.f/128.f);
    const float var  = s2 * (1.f/128.f) - mu*mu;
    const float rstd = rsqrtf(var + LN_EPS);
#pragma unroll
    for(int u=0;u<4;u++){
      const int kb = q*64 + u*16;
      const int c0 = (kb ^ ((row&7)<<4)) >> 1;    // de-swizzled channel of this 16B block
      uint16_t h[8];
#pragma unroll
      for(int j=0;j<8;j++)
        h[j] = f2bf((xs[u*8+j]-mu)*rstd*lncw[c0+j] + lncb[c0+j]);
      uint4 pk;
      pk.x = (uint32_t)h[0] | ((uint32_t)h[1]<<16);
      pk.y = (uint32_t)h[2] | ((uint32_t)h[3]<<16);
      pk.z = (uint32_t)h[4] | ((uint32_t)h[5]<<16);
      pk.w = (uint32_t)h[6] | ((uint32_t)h[7]<<16);
      const int byte = row*256 + (kb ^ ((row&7)<<4));
      *(uint4*)((char*)sT2 + byte) = pk;
    }
  }

  const int wm = wid >> 1, wn = wid & 1;
  const int l15 = lane & 15, lh = lane >> 4;
  const f32x4 z4 = {0.f,0.f,0.f,0.f};

  // ---- gating gemm from sGA (ready since barrier above; sGA not modified) ----
  f32x4 accG[2][4];
#pragma unroll
  for(int a=0;a<2;a++) for(int b=0;b<4;b++) accG[a][b]=z4;
  {
    const uint16_t* Wg = wbf + 4*16384;   // gating_w bf16
#pragma unroll
    for(int ks=0;ks<4;ks++){
      bf16x8 af[2];
#pragma unroll
      for(int tm=0;tm<2;tm++){
        const int row = wm*32 + tm*16 + l15;
        const int byte = row*256 + ((ks*64 + lh*16) ^ ((row&7)<<4));
        af[tm] = *(const bf16x8*)((const char*)sGA + byte);
      }
#pragma unroll
      for(int tn=0;tn<4;tn++){
        const int o = wn*64 + tn*16 + l15;
        const bf16x8 bw = *(const bf16x8*)(Wg + o*128 + ks*32 + lh*8);
#pragma unroll
        for(int tm=0;tm<2;tm++)
          accG[tm][tn] = __builtin_amdgcn_mfma_f32_16x16x32_bf16(af[tm], bw, accG[tm][tn], 0,0,0);
      }
    }
  }
  __syncthreads();   // LN_c(t) writes complete before out-gemm reads sT2

  // ---- out_proj gemm + fused epilogue ----
  f32x4 acc[2][4];
#pragma unroll
  for(int a=0;a<2;a++) for(int b=0;b<4;b++) acc[a][b]=z4;
  {
    const uint16_t* W = wbf + 5*16384;    // out_proj_w bf16
#pragma unroll
    for(int ks=0;ks<4;ks++){
      bf16x8 af[2];
#pragma unroll
      for(int tm=0;tm<2;tm++){
        const int row = wm*32 + tm*16 + l15;
        const int byte = row*256 + ((ks*64 + lh*16) ^ ((row&7)<<4));
        af[tm] = *(const bf16x8*)((const char*)sT2 + byte);
      }
#pragma unroll
      for(int tn=0;tn<4;tn++){
        const int o = wn*64 + tn*16 + l15;
        const bf16x8 bw = *(const bf16x8*)(W + o*128 + ks*32 + lh*8);
#pragma unroll
        for(int tm=0;tm<2;tm++)
          acc[tm][tn] = __builtin_amdgcn_mfma_f32_16x16x32_bf16(af[tm], bw, acc[tm][tn], 0,0,0);
      }
    }
  }
#pragma unroll
  for(int tm=0;tm<2;tm++){
#pragma unroll
    for(int tn=0;tn<4;tn++){
      const int col = wn*64 + tn*16 + l15;
      const float obv = opb[col];
      const float gbias = gB[col];
#pragma unroll
      for(int r=0;r<4;r++){
        const int row = wm*32 + tm*16 + lh*4 + r;
        const size_t p = (size_t)(pbase + row);
        out[p*128 + col] = (acc[tm][tn][r] + obv) * sigm(accG[tm][tn][r] + gbias);
      }
    }
  }
}

// ---------------- launch ----------------
extern "C" void kernel_launch(void* const* d_in, const int* in_sizes, int n_in,
                              void* d_out, int out_size, void* d_ws, size_t ws_size,
                              hipStream_t stream)
{
  (void)in_sizes; (void)n_in; (void)out_size; (void)ws_size;
  const float* act   = (const float*)d_in[0];
  const float* mask  = (const float*)d_in[1];
  const float* lnw   = (const float*)d_in[2];
  const float* lnb   = (const float*)d_in[3];
  const float* lpw   = (const float*)d_in[4];
  const float* lpb   = (const float*)d_in[5];
  const float* rpw   = (const float*)d_in[6];
  const float* rpb   = (const float*)d_in[7];
  const float* lgw   = (const float*)d_in[8];
  const float* lgb   = (const float*)d_in[9];
  const float* rgw   = (const float*)d_in[10];
  const float* rgb   = (const float*)d_in[11];
  const float* lncw  = (const float*)d_in[12];
  const float* lncb  = (const float*)d_in[13];
  const float* opw   = (const float*)d_in[14];
  const float* opb   = (const float*)d_in[15];
  const float* gw    = (const float*)d_in[16];
  const float* gb    = (const float*)d_in[17];

  char* ws = (char*)d_ws;
  uint16_t* leftT  = (uint16_t*)(ws);                      // 64MB [C][N*N] bf16, PRE-SWIZZLED
  uint16_t* rightT = (uint16_t*)(ws + ((size_t)64<<20));   // 64MB, PRE-SWIZZLED
  uint16_t* tbuf   = (uint16_t*)(ws + ((size_t)128<<20));  // 64MB [C][N*N] bf16 plain
  uint16_t* wbf    = (uint16_t*)(ws + ((size_t)192<<20));  // 192KB: 6 bf16 weight mats

  wconv_k<<<384, 256, 0, stream>>>(lpw, lgw, rpw, rgw, gw, opw, wbf);
  k1_proj<<<1024, 1024, 0, stream>>>(act, mask, lnw, lnb, lpb, lgb, rpb, rgb,
                                     wbf, leftT, rightT);
  k2_tri<<<2048, 256, 0, stream>>>(leftT, rightT, tbuf);
  k3_out<<<4096, 256, 0, stream>>>(tbuf, act, lnw, lnb, lncw, lncb, wbf, opb, gb,
                                   (float*)d_out);
}